// Round 1
// baseline (1160.391 us; speedup 1.0000x reference)
//
#include <hip/hip_runtime.h>

#define HH 256
#define WW 256
#define C_IN 64      // C
#define C2 128       // 2C
#define NPX 100      // 10x10 halo pixels
#define XS 104       // xnT row stride (floats), 16B-aligned quads
#define O2S 132      // out2 row stride
#define WTS 36       // conv weight-chunk transposed stride
#define PRS 36       // pre-halo stride
#define QS 65        // qT/kT/vT row stride (odd -> conflict-free columns)

__global__ __launch_bounds__(512, 2)
void event_fsas_fused(
    const float* __restrict__ x, const float* __restrict__ evt,
    const float* __restrict__ w_q, const float* __restrict__ w_kv,
    const float* __restrict__ w_qdw, const float* __restrict__ w_kvdw,
    const float* __restrict__ w_proj,
    const float* __restrict__ ln_img_w, const float* __restrict__ ln_img_b,
    const float* __restrict__ ln_evt_w, const float* __restrict__ ln_evt_b,
    const float* __restrict__ ln_out_w, const float* __restrict__ ln_out_b,
    float* __restrict__ out)
{
    // LDS plan (floats):
    //   s_a   : xnT[64][104] (LN'd input, transposed)  -> later out2[64][132]
    //   s_w   : conv1x1 weight chunk transposed [64][36]
    //   s_pre : conv1x1 halo output chunk [100][36]
    //   s_q   : qT[128][65]   -> later w_projT [128][64] (XOR-swizzled)
    //   s_k   : kT[128][65]   -> later yT [128][64]
    //   s_v   : vT[128][65]
    __shared__ float s_a[8448];
    __shared__ float s_w[2560];
    __shared__ float s_pre[NPX * PRS];
    __shared__ float s_q[C2 * QS];
    __shared__ float s_k[C2 * QS];
    __shared__ float s_v[C2 * QS];
    __shared__ float s_mu[64];
    __shared__ float s_inv[64];

    const int tid = threadIdx.x;
    const int pj = blockIdx.x, pi = blockIdx.y, b = blockIdx.z;
    const int h0 = pi * 8, w0 = pj * 8;

    // ================= q path (x) and kv path (evt) =================
    for (int path = 0; path < 2; ++path) {
        const float* src  = (path == 0) ? x : evt;
        const float* lw   = (path == 0) ? ln_img_w : ln_evt_w;
        const float* lb   = (path == 0) ? ln_img_b : ln_evt_b;
        const float* wm   = (path == 0) ? w_q : w_kv;
        const float* wdwm = (path == 0) ? w_qdw : w_kvdw;
        const int nchunk  = (path == 0) ? 4 : 8;

        // ---- load 10x10 halo (OOB -> 0), layout xnT[c][px] ----
        for (int idx = tid; idx < C_IN * NPX; idx += 512) {
            int c = idx / NPX, px = idx - c * NPX;
            int gh = h0 - 1 + px / 10, gw = w0 - 1 + px % 10;
            float v = 0.f;
            if (gh >= 0 && gh < HH && gw >= 0 && gw < WW)
                v = src[((b * C_IN + c) * HH + gh) * WW + gw];
            s_a[c * XS + px] = v;
        }
        __syncthreads();
        // ---- channel LayerNorm per pixel (skip OOB: must stay exactly 0) ----
        if (tid < NPX) {
            int px = tid;
            int gh = h0 - 1 + px / 10, gw = w0 - 1 + px % 10;
            if (gh >= 0 && gh < HH && gw >= 0 && gw < WW) {
                float s = 0.f, s2 = 0.f;
                #pragma unroll 8
                for (int c = 0; c < C_IN; ++c) {
                    float v = s_a[c * XS + px];
                    s += v; s2 += v * v;
                }
                float mu  = s  * (1.f / 64.f);
                float var = s2 * (1.f / 64.f) - mu * mu;
                float inv = rsqrtf(var + 1e-5f);
                #pragma unroll 8
                for (int c = 0; c < C_IN; ++c) {
                    float v = s_a[c * XS + px];
                    s_a[c * XS + px] = (v - mu) * inv * lw[c] + lb[c];
                }
            }
        }
        __syncthreads();

        // ---- conv1x1 (o-chunks of 32) + depthwise 3x3 ----
        for (int och = 0; och < nchunk; ++och) {
            // stage transposed weight chunk: s_w[c][oo] = wm[och*32+oo][c]
            for (int idx = tid; idx < 32 * C_IN; idx += 512) {
                int oo = idx >> 6, c = idx & 63;
                s_w[c * WTS + oo] = wm[(och * 32 + oo) * C_IN + c];
            }
            __syncthreads();
            // conv1x1 on 100 halo pixels: tasks = 25 px-quads x 8 o-quads
            if (tid < 200) {
                int pxq = tid >> 3, oq = tid & 7;
                float acc[4][4] = {{0.f}};
                #pragma unroll 8
                for (int c = 0; c < C_IN; ++c) {
                    float4 xv = *(const float4*)&s_a[c * XS + 4 * pxq];
                    float4 wv = *(const float4*)&s_w[c * WTS + 4 * oq];
                    acc[0][0] += xv.x * wv.x; acc[0][1] += xv.x * wv.y;
                    acc[0][2] += xv.x * wv.z; acc[0][3] += xv.x * wv.w;
                    acc[1][0] += xv.y * wv.x; acc[1][1] += xv.y * wv.y;
                    acc[1][2] += xv.y * wv.z; acc[1][3] += xv.y * wv.w;
                    acc[2][0] += xv.z * wv.x; acc[2][1] += xv.z * wv.y;
                    acc[2][2] += xv.z * wv.z; acc[2][3] += xv.z * wv.w;
                    acc[3][0] += xv.w * wv.x; acc[3][1] += xv.w * wv.y;
                    acc[3][2] += xv.w * wv.z; acc[3][3] += xv.w * wv.w;
                }
                #pragma unroll
                for (int i = 0; i < 4; ++i)
                    *(float4*)&s_pre[(4 * pxq + i) * PRS + 4 * oq] =
                        make_float4(acc[i][0], acc[i][1], acc[i][2], acc[i][3]);
            }
            __syncthreads();
            // depthwise 3x3 (cross-correlation, halo gives SAME padding)
            {
                int oo = tid & 31;
                int og = och * 32 + oo;
                float wdw[9];
                #pragma unroll
                for (int t = 0; t < 9; ++t) wdw[t] = wdwm[og * 9 + t];
                float* dst;
                if (path == 0)      dst = &s_q[og * QS];
                else if (og < C2)   dst = &s_k[og * QS];
                else                dst = &s_v[(og - C2) * QS];
                #pragma unroll
                for (int it = 0; it < 4; ++it) {
                    int p = (tid >> 5) + it * 16;
                    int pr = p >> 3, pc = p & 7;
                    float s = 0.f;
                    #pragma unroll
                    for (int dh = 0; dh < 3; ++dh)
                        #pragma unroll
                        for (int dw = 0; dw < 3; ++dw)
                            s += s_pre[((pr + dh) * 10 + (pc + dw)) * PRS + oo] * wdw[dh * 3 + dw];
                    dst[p] = s;
                }
            }
            __syncthreads();
        }
    }

    // ============ 8x8 circular conv: out2[p][c] = sum_t q[t][c]*k[(p-t)%8][c] ============
    #pragma unroll
    for (int it = 0; it < 2; ++it) {
        int task = tid + it * 512;
        int c = task & 127, pr = task >> 7;
        float qreg[64];
        #pragma unroll
        for (int t = 0; t < 64; ++t) qreg[t] = s_q[c * QS + t];
        float acc[8] = {0.f, 0.f, 0.f, 0.f, 0.f, 0.f, 0.f, 0.f};
        #pragma unroll
        for (int tr = 0; tr < 8; ++tr) {
            int rrow = (pr - tr) & 7;
            float kk[8];
            #pragma unroll
            for (int j = 0; j < 8; ++j) kk[j] = s_k[c * QS + rrow * 8 + j];
            #pragma unroll
            for (int tc = 0; tc < 8; ++tc) {
                float qv = qreg[tr * 8 + tc];
                #pragma unroll
                for (int pc = 0; pc < 8; ++pc)
                    acc[pc] += qv * kk[(pc - tc) & 7];
            }
        }
        #pragma unroll
        for (int pc = 0; pc < 8; ++pc)
            s_a[(pr * 8 + pc) * O2S + c] = acc[pc];
    }
    __syncthreads();

    // ============ LayerNorm over 2C channels ============
    if (tid < 64) {
        int px = tid;
        float s = 0.f, s2 = 0.f;
        #pragma unroll 8
        for (int c = 0; c < C2; ++c) {
            float v = s_a[px * O2S + c];
            s += v; s2 += v * v;
        }
        float mu  = s  * (1.f / 128.f);
        float var = s2 * (1.f / 128.f) - mu * mu;
        s_mu[px]  = mu;
        s_inv[px] = rsqrtf(var + 1e-5f);
    }
    __syncthreads();

    // y = ln(out2)*v -> yT in s_k (stride 64); w_projT -> s_q (stride 64, XOR swizzle)
    for (int idx = tid; idx < 64 * C2; idx += 512) {
        int px = idx & 63, c = idx >> 6;
        float v = s_a[px * O2S + c];
        float y = (v - s_mu[px]) * s_inv[px] * ln_out_w[c] + ln_out_b[c];
        s_k[c * 64 + px] = y * s_v[c * QS + px];
    }
    for (int idx = tid; idx < 64 * C2; idx += 512) {
        int o = idx >> 7, c = idx & 127;
        s_q[c * 64 + (o ^ (c & 28))] = w_proj[o * C2 + c];
    }
    __syncthreads();

    // ============ final conv1x1: out[p][o] = sum_c y[p][c] * w_proj[o][c] ============
    {
        int pxp = tid >> 4, oq = tid & 15;  // 32 px-pairs x 16 o-quads = 512 tasks
        float acc[2][4] = {{0.f}};
        #pragma unroll 8
        for (int c = 0; c < C2; ++c) {
            float4 wv = *(const float4*)&s_q[c * 64 + ((4 * oq) ^ (c & 28))];
            float y0 = s_k[c * 64 + 2 * pxp];
            float y1 = s_k[c * 64 + 2 * pxp + 1];
            acc[0][0] += y0 * wv.x; acc[0][1] += y0 * wv.y;
            acc[0][2] += y0 * wv.z; acc[0][3] += y0 * wv.w;
            acc[1][0] += y1 * wv.x; acc[1][1] += y1 * wv.y;
            acc[1][2] += y1 * wv.z; acc[1][3] += y1 * wv.w;
        }
        int px0 = 2 * pxp;
        int gh = h0 + (px0 >> 3), gw = w0 + (px0 & 7);
        #pragma unroll
        for (int j = 0; j < 4; ++j) {
            int o = 4 * oq + j;
            float2 vv = make_float2(acc[0][j], acc[1][j]);
            *(float2*)&out[((b * C_IN + o) * HH + gh) * WW + gw] = vv;
        }
    }
}

extern "C" void kernel_launch(void* const* d_in, const int* in_sizes, int n_in,
                              void* d_out, int out_size, void* d_ws, size_t ws_size,
                              hipStream_t stream) {
    (void)in_sizes; (void)n_in; (void)d_ws; (void)ws_size; (void)out_size;
    const float* x        = (const float*)d_in[0];
    const float* evt      = (const float*)d_in[1];
    const float* w_q      = (const float*)d_in[2];
    const float* w_kv     = (const float*)d_in[3];
    const float* w_qdw    = (const float*)d_in[4];
    const float* w_kvdw   = (const float*)d_in[5];
    const float* w_proj   = (const float*)d_in[6];
    const float* ln_img_w = (const float*)d_in[7];
    const float* ln_img_b = (const float*)d_in[8];
    const float* ln_evt_w = (const float*)d_in[9];
    const float* ln_evt_b = (const float*)d_in[10];
    const float* ln_out_w = (const float*)d_in[11];
    const float* ln_out_b = (const float*)d_in[12];
    float* out = (float*)d_out;

    dim3 grid(32, 32, 4);   // (pj, pi, b)
    dim3 block(512);
    hipLaunchKernelGGL(event_fsas_fused, grid, block, 0, stream,
                       x, evt, w_q, w_kv, w_qdw, w_kvdw, w_proj,
                       ln_img_w, ln_img_b, ln_evt_w, ln_evt_b, ln_out_w, ln_out_b,
                       out);
}

// Round 2
// 523.734 us; speedup vs baseline: 2.2156x; 2.2156x over previous
//
#include <hip/hip_runtime.h>

typedef __attribute__((ext_vector_type(8))) short bf16x8;
typedef __attribute__((ext_vector_type(4))) float f32x4;
typedef __attribute__((ext_vector_type(4))) unsigned int u32x4;

__device__ __forceinline__ unsigned short f2bf(float f) {
    union { float f; unsigned int u; } v; v.f = f;
    return (unsigned short)((v.u + 0x7fffu + ((v.u >> 16) & 1u)) >> 16);
}
__device__ __forceinline__ float bflo(unsigned int u) {
    union { unsigned int u; float f; } v; v.u = u << 16; return v.f;
}
__device__ __forceinline__ float bfhi(unsigned int u) {
    union { unsigned int u; float f; } v; v.u = u & 0xffff0000u; return v.f;
}

// ---------------------------------------------------------------------------
// Producer: LN(chan) -> conv1x1 (MFMA bf16, 128 out-ch) -> depthwise 3x3
// One 8x8 output tile per block, 10x10 halo recomputed.
// dst layout: [b][h][w][128] bf16
// ---------------------------------------------------------------------------
#define P_OFF_A    0        // ushort A[112][64] swizzled (14336 B)
#define P_OFF_WB   14336    // ushort Wb[128][64] swizzled (16384 B)
#define P_OFF_X    30720    // float xf[64][101] (25856 B) / ushort pre[100][128] (25600 B)
#define P_OFF_WDW  56576    // float swdw[1152] (4608 B)
#define P_OFF_LNW  61184
#define P_OFF_LNB  61440
#define P_OFF_MU   61696
#define P_OFF_INV  62112
#define P_SMEM     62528

__global__ __launch_bounds__(512, 4)
void prod_kernel(const float* __restrict__ src, const float* __restrict__ wmat,
                 const float* __restrict__ wdw, const float* __restrict__ lnw,
                 const float* __restrict__ lnb, unsigned short* __restrict__ dst)
{
    __shared__ __align__(16) char smem[P_SMEM];
    unsigned short* A   = (unsigned short*)(smem + P_OFF_A);
    unsigned short* Wb  = (unsigned short*)(smem + P_OFF_WB);
    float* xf           = (float*)(smem + P_OFF_X);
    unsigned short* pre = (unsigned short*)(smem + P_OFF_X);   // overlays xf (dead)
    float* swdw = (float*)(smem + P_OFF_WDW);
    float* slnw = (float*)(smem + P_OFF_LNW);
    float* slnb = (float*)(smem + P_OFF_LNB);
    float* smu  = (float*)(smem + P_OFF_MU);
    float* sinv = (float*)(smem + P_OFF_INV);

    const int tid = threadIdx.x;
    const int b = blockIdx.z, ti = blockIdx.y, tj = blockIdx.x;
    const int h0 = ti * 8, w0 = tj * 8;

    if (tid < 64) slnw[tid] = lnw[tid];
    else if (tid < 128) slnb[tid - 64] = lnb[tid - 64];
    for (int i = tid; i < 1152; i += 512) swdw[i] = wdw[i];
    for (int i = tid; i < 8192; i += 512) {
        int o = i >> 6, c = i & 63;
        Wb[o * 64 + (((c >> 3) ^ (o & 7)) << 3) + (c & 7)] = f2bf(wmat[i]);
    }
    for (int i = tid; i < 6400; i += 512) {
        int c = i / 100, px = i - c * 100;
        int r = px / 10, cc = px - r * 10;
        int gh = h0 - 1 + r, gw = w0 - 1 + cc;
        float v = 0.f;
        if (gh >= 0 && gh < 256 && gw >= 0 && gw < 256)
            v = src[((b * 64 + c) * 256 + gh) * 256 + gw];
        xf[c * 101 + px] = v;
    }
    for (int i = tid; i < 768; i += 512) A[6400 + i] = 0;   // zero pad rows 100..111
    __syncthreads();

    // per-pixel LN stats over 64 channels (OOB rows are all-zero -> finite stats)
    if (tid < 100) {
        float s = 0.f, s2 = 0.f;
        #pragma unroll
        for (int c = 0; c < 64; ++c) { float v = xf[c * 101 + tid]; s += v; s2 += v * v; }
        float mu = s * (1.f / 64.f);
        float var = s2 * (1.f / 64.f) - mu * mu;
        smu[tid] = mu; sinv[tid] = rsqrtf(var + 1e-5f);
    }
    __syncthreads();

    // apply LN, pack bf16 into swizzled A; OOB pixels -> 0 (so conv1x1 output = 0 = SAME pad)
    for (int i = tid; i < 6400; i += 512) {
        int c = i & 63, px = i >> 6;
        int r = px / 10, cc = px - r * 10;
        int gh = h0 - 1 + r, gw = w0 - 1 + cc;
        bool valid = (gh >= 0 && gh < 256 && gw >= 0 && gw < 256);
        float v = (xf[c * 101 + px] - smu[px]) * sinv[px] * slnw[c] + slnb[c];
        A[px * 64 + (((c >> 3) ^ (px & 7)) << 3) + (c & 7)] =
            valid ? f2bf(v) : (unsigned short)0;
    }
    __syncthreads();

    // MFMA: [112px x 64c] x [64c x 128o]; wave w owns o-tile w
    const int lane = tid & 63;
    const int l15 = lane & 15, l4 = lane >> 4;
    const int o_n = (tid >> 6) * 16 + l15;
    f32x4 acc[7];
    #pragma unroll
    for (int mt = 0; mt < 7; ++mt) acc[mt] = (f32x4){0.f, 0.f, 0.f, 0.f};
    #pragma unroll
    for (int ks = 0; ks < 2; ++ks) {
        int cch = ks * 4 + l4;
        bf16x8 bfrag = *(const bf16x8*)&Wb[o_n * 64 + ((cch ^ (o_n & 7)) << 3)];
        #pragma unroll
        for (int mt = 0; mt < 7; ++mt) {
            int px = mt * 16 + l15;
            bf16x8 afrag = *(const bf16x8*)&A[px * 64 + ((cch ^ (px & 7)) << 3)];
            acc[mt] = __builtin_amdgcn_mfma_f32_16x16x32_bf16(afrag, bfrag, acc[mt], 0, 0, 0);
        }
    }
    // C -> pre (bf16, swizzled), rows >= 100 discarded
    #pragma unroll
    for (int mt = 0; mt < 7; ++mt) {
        #pragma unroll
        for (int r = 0; r < 4; ++r) {
            int px = mt * 16 + l4 * 4 + r;
            if (px < 100)
                pre[px * 128 + (((o_n >> 3) ^ (px & 7)) << 3) + (o_n & 7)] = f2bf(acc[mt][r]);
        }
    }
    __syncthreads();

    // depthwise 3x3 (correlation) + store; each thread owns an o-pair
    {
        const int opair = tid & 63, o = opair * 2;
        float wd0[9], wd1[9];
        #pragma unroll
        for (int t = 0; t < 9; ++t) { wd0[t] = swdw[o * 9 + t]; wd1[t] = swdw[o * 9 + 9 + t]; }
        const int och = o >> 3, osub = o & 7;
        #pragma unroll
        for (int i = 0; i < 8; ++i) {
            int px = (tid >> 6) + 8 * i;
            int pr = px >> 3, pc = px & 7;
            float a0 = 0.f, a1 = 0.f;
            #pragma unroll
            for (int dh = 0; dh < 3; ++dh)
                #pragma unroll
                for (int dwi = 0; dwi < 3; ++dwi) {
                    int hp = (pr + dh) * 10 + (pc + dwi);
                    unsigned int u = *(const unsigned int*)&pre[hp * 128 + ((och ^ (hp & 7)) << 3) + osub];
                    a0 += bflo(u) * wd0[dh * 3 + dwi];
                    a1 += bfhi(u) * wd1[dh * 3 + dwi];
                }
            unsigned int outw = (unsigned int)f2bf(a0) | ((unsigned int)f2bf(a1) << 16);
            *(unsigned int*)&dst[(((b * 256 + h0 + pr) * 256) + (w0 + pc)) * 128 + o] = outw;
        }
    }
}

// ---------------------------------------------------------------------------
// Patch kernel: 8x8 circular conv + LN(2C) + *v + proj conv1x1 (MFMA)
// ---------------------------------------------------------------------------
#define K_OFF_Q   0        // sq[64][128] ushort (16384) ; later sv
#define K_OFF_K   16384    // sk ; later sy (swizzled)
#define K_OFF_C   32768    // out2 f32 [64][129] (33024) ; later swp(16384)+sc(16896)
#define K_OFF_MU  66048
#define K_OFF_IV  66304
#define K_OFF_LW  66560
#define K_OFF_LB  67072
#define K_SMEM    67584

__global__ __launch_bounds__(256, 2)
void patch_kernel(const unsigned short* __restrict__ qb,
                  const unsigned short* __restrict__ kb,
                  const unsigned short* __restrict__ vb,
                  const float* __restrict__ w_proj,
                  const float* __restrict__ lnw, const float* __restrict__ lnb,
                  float* __restrict__ out)
{
    __shared__ __align__(16) char smem[K_SMEM];
    unsigned short* sq = (unsigned short*)(smem + K_OFF_Q);
    unsigned short* sk = (unsigned short*)(smem + K_OFF_K);
    unsigned short* sv = sq;                                   // overlays sq (dead)
    unsigned short* sy = sk;                                   // overlays sk (dead)
    float* out2        = (float*)(smem + K_OFF_C);
    unsigned short* swp = (unsigned short*)(smem + K_OFF_C);   // overlays out2 (dead)
    float* sc          = (float*)(smem + K_OFF_C + 16384);
    float* smu = (float*)(smem + K_OFF_MU);
    float* siv = (float*)(smem + K_OFF_IV);
    float* slw = (float*)(smem + K_OFF_LW);
    float* slb = (float*)(smem + K_OFF_LB);

    const int tid = threadIdx.x;
    const int b = blockIdx.z, ti = blockIdx.y, tj = blockIdx.x;
    const int h0 = ti * 8, w0 = tj * 8;
    const int pbase = ((b * 256 + h0) * 256 + w0) * 128;

    float wreg[32];
    #pragma unroll
    for (int j = 0; j < 32; ++j) wreg[j] = w_proj[j * 256 + tid];
    if (tid < 128) { slw[tid] = lnw[tid]; slb[tid] = lnb[tid]; }

    #pragma unroll
    for (int it = 0; it < 4; ++it) {
        int idx = tid + it * 256;
        int px = idx >> 4, ch = idx & 15;
        int goff = pbase + ((px >> 3) * 256 + (px & 7)) * 128 + ch * 8;
        *(u32x4*)&sq[px * 128 + ch * 8] = *(const u32x4*)&qb[goff];
        *(u32x4*)&sk[px * 128 + ch * 8] = *(const u32x4*)&kb[goff];
    }
    __syncthreads();

    // circular conv: out2[p][c] = sum_t q[t][c] k[(p-t)%8][c]; thread = (c-quad, pr)
    {
        const int cq = tid & 31, pr = tid >> 5;
        float acc[8][4];
        #pragma unroll
        for (int pc = 0; pc < 8; ++pc)
            #pragma unroll
            for (int ci = 0; ci < 4; ++ci) acc[pc][ci] = 0.f;
        #pragma unroll
        for (int tr = 0; tr < 8; ++tr) {
            float qv[8][4], kv[8][4];
            #pragma unroll
            for (int tc = 0; tc < 8; ++tc) {
                unsigned long long u = *(const unsigned long long*)&sq[(tr * 8 + tc) * 128 + cq * 4];
                unsigned int ulo = (unsigned int)u, uhi = (unsigned int)(u >> 32);
                qv[tc][0] = bflo(ulo); qv[tc][1] = bfhi(ulo);
                qv[tc][2] = bflo(uhi); qv[tc][3] = bfhi(uhi);
            }
            int rrow = (pr - tr) & 7;
            #pragma unroll
            for (int j = 0; j < 8; ++j) {
                unsigned long long u = *(const unsigned long long*)&sk[(rrow * 8 + j) * 128 + cq * 4];
                unsigned int ulo = (unsigned int)u, uhi = (unsigned int)(u >> 32);
                kv[j][0] = bflo(ulo); kv[j][1] = bfhi(ulo);
                kv[j][2] = bflo(uhi); kv[j][3] = bfhi(uhi);
            }
            #pragma unroll
            for (int tc = 0; tc < 8; ++tc)
                #pragma unroll
                for (int pc = 0; pc < 8; ++pc) {
                    const int j = (pc - tc) & 7;
                    #pragma unroll
                    for (int ci = 0; ci < 4; ++ci)
                        acc[pc][ci] += qv[tc][ci] * kv[j][ci];
                }
        }
        #pragma unroll
        for (int pc = 0; pc < 8; ++pc)
            #pragma unroll
            for (int ci = 0; ci < 4; ++ci)
                out2[(pr * 8 + pc) * 129 + cq * 4 + ci] = acc[pc][ci];
    }
    __syncthreads();

    // load v into freed sq region; LN stats over 128 channels
    #pragma unroll
    for (int it = 0; it < 4; ++it) {
        int idx = tid + it * 256;
        int px = idx >> 4, ch = idx & 15;
        int goff = pbase + ((px >> 3) * 256 + (px & 7)) * 128 + ch * 8;
        *(u32x4*)&sv[px * 128 + ch * 8] = *(const u32x4*)&vb[goff];
    }
    if (tid < 64) {
        float s = 0.f, s2 = 0.f;
        #pragma unroll 16
        for (int c = 0; c < 128; ++c) { float v = out2[tid * 129 + c]; s += v; s2 += v * v; }
        float mu = s * (1.f / 128.f);
        float var = s2 * (1.f / 128.f) - mu * mu;
        smu[tid] = mu; siv[tid] = rsqrtf(var + 1e-5f);
    }
    __syncthreads();

    // y = LN(out2)*v -> sy (bf16, swizzled, overlays sk)
    for (int i = tid; i < 8192; i += 256) {
        int px = i >> 7, c = i & 127;
        float t = (out2[px * 129 + c] - smu[px]) * siv[px] * slw[c] + slb[c];
        float vv = bflo((unsigned int)sv[px * 128 + c]);
        sy[px * 128 + (((c >> 3) ^ (px & 7)) << 3) + (c & 7)] = f2bf(t * vv);
    }
    __syncthreads();

    // stage w_proj (from regs) -> swp (overlays dead out2)
    #pragma unroll
    for (int j = 0; j < 32; ++j) {
        int idx = j * 256 + tid;
        int o = idx >> 7, c = idx & 127;
        swp[o * 128 + (((c >> 3) ^ (o & 7)) << 3) + (c & 7)] = f2bf(wreg[j]);
    }
    __syncthreads();

    // proj MFMA: [64px x 128c] x [128c x 64o]
    {
        const int lane = tid & 63;
        const int l15 = lane & 15, l4 = lane >> 4;
        const int wave = tid >> 6;
        f32x4 pacc[4];
        #pragma unroll
        for (int nt = 0; nt < 4; ++nt) pacc[nt] = (f32x4){0.f, 0.f, 0.f, 0.f};
        const int px_a = wave * 16 + l15;
        #pragma unroll
        for (int ks = 0; ks < 4; ++ks) {
            int cch = ks * 4 + l4;
            bf16x8 af = *(const bf16x8*)&sy[px_a * 128 + ((cch ^ (px_a & 7)) << 3)];
            #pragma unroll
            for (int nt = 0; nt < 4; ++nt) {
                int o = nt * 16 + l15;
                bf16x8 bf_ = *(const bf16x8*)&swp[o * 128 + ((cch ^ (o & 7)) << 3)];
                pacc[nt] = __builtin_amdgcn_mfma_f32_16x16x32_bf16(af, bf_, pacc[nt], 0, 0, 0);
            }
        }
        #pragma unroll
        for (int nt = 0; nt < 4; ++nt)
            #pragma unroll
            for (int r = 0; r < 4; ++r) {
                int px = wave * 16 + l4 * 4 + r;
                int o = nt * 16 + l15;
                sc[px * 66 + o] = pacc[nt][r];
            }
    }
    __syncthreads();

    // coalesced-ish store: per (o, out-row): 8 contiguous floats
    #pragma unroll
    for (int it = 0; it < 2; ++it) {
        int task = tid + it * 256;
        int o = task & 63, r = task >> 6;
        float v0[4], v1[4];
        #pragma unroll
        for (int j = 0; j < 4; ++j) {
            v0[j] = sc[(r * 8 + j) * 66 + o];
            v1[j] = sc[(r * 8 + 4 + j) * 66 + o];
        }
        int obase = ((b * 64 + o) * 256 + h0 + r) * 256 + w0;
        *(f32x4*)&out[obase]     = (f32x4){v0[0], v0[1], v0[2], v0[3]};
        *(f32x4*)&out[obase + 4] = (f32x4){v1[0], v1[1], v1[2], v1[3]};
    }
}

extern "C" void kernel_launch(void* const* d_in, const int* in_sizes, int n_in,
                              void* d_out, int out_size, void* d_ws, size_t ws_size,
                              hipStream_t stream) {
    (void)in_sizes; (void)n_in; (void)out_size; (void)ws_size;
    const float* x        = (const float*)d_in[0];
    const float* evt      = (const float*)d_in[1];
    const float* w_q      = (const float*)d_in[2];
    const float* w_kv     = (const float*)d_in[3];
    const float* w_qdw    = (const float*)d_in[4];
    const float* w_kvdw   = (const float*)d_in[5];
    const float* w_proj   = (const float*)d_in[6];
    const float* ln_img_w = (const float*)d_in[7];
    const float* ln_img_b = (const float*)d_in[8];
    const float* ln_evt_w = (const float*)d_in[9];
    const float* ln_evt_b = (const float*)d_in[10];
    const float* ln_out_w = (const float*)d_in[11];
    const float* ln_out_b = (const float*)d_in[12];
    float* out = (float*)d_out;

    // workspace: q/k/v post-dw, each [4][256][256][128] bf16 = 67,108,864 B (201 MB total)
    unsigned short* qd = (unsigned short*)d_ws;
    unsigned short* kd = qd + (size_t)4 * 256 * 256 * 128;
    unsigned short* vd = kd + (size_t)4 * 256 * 256 * 128;

    dim3 pgrid(32, 32, 4), pblk(512);
    hipLaunchKernelGGL(prod_kernel, pgrid, pblk, 0, stream,
                       x,   w_q,             w_qdw,           ln_img_w, ln_img_b, qd);
    hipLaunchKernelGGL(prod_kernel, pgrid, pblk, 0, stream,
                       evt, w_kv,            w_kvdw,          ln_evt_w, ln_evt_b, kd);
    hipLaunchKernelGGL(prod_kernel, pgrid, pblk, 0, stream,
                       evt, w_kv + 128 * 64, w_kvdw + 128 * 9, ln_evt_w, ln_evt_b, vd);
    dim3 kgrid(32, 32, 4), kblk(256);
    hipLaunchKernelGGL(patch_kernel, kgrid, kblk, 0, stream,
                       qd, kd, vd, w_proj, ln_out_w, ln_out_b, out);
}